// Round 2
// baseline (854.044 us; speedup 1.0000x reference)
//
#include <hip/hip_runtime.h>
#include <math.h>

// Problem shape (fixed by the harness/reference):
#define BB 8
#define NN 8192
#define MM 8192
// D = 3

#define ROW_TILE 128      // rows per block (8 per thread, 16 ty)
#define COL_TILE 2048     // cols per block
#define CHUNK    128      // preds staged per iteration
#define INF_BITS 0x7F800000

// d_ws layout:
//   float accum[2]  : [0]=sum_g2p, [1]=sum_p2g
//   int   ticket    : at accum[2]
//   +64B  int minn[BB*NN]; int minp[BB*MM]   (float-bits, int-min trick)

__global__ void chamfer_init(int* __restrict__ mins, float* __restrict__ accum) {
    int idx = blockIdx.x * blockDim.x + threadIdx.x;
    if (idx < BB * (NN + MM)) mins[idx] = INF_BITS;
    if (idx < 2) accum[idx] = 0.0f;
    if (idx == 2) ((int*)accum)[2] = 0;
}

__global__ __launch_bounds__(256, 7) void chamfer_main(
    const float* __restrict__ gts, const float* __restrict__ preds,
    int* __restrict__ minn, int* __restrict__ minp)
{
    __shared__ float4 sp[2][CHUNK];     // double-buffered pred chunk: x,y,z,-|p|^2/2
    __shared__ int colmin[COL_TILE];    // block-local col mins (float bits, int-min)

    const int b       = blockIdx.z;
    const int rowBase = blockIdx.x * ROW_TILE;
    const int colBase = blockIdx.y * COL_TILE;
    const int tid  = threadIdx.x;
    const int tx   = tid & 15;
    const int ty   = tid >> 4;
    const int lane = tid & 63;

    const float kInf = __builtin_inff();

    // This thread's 8 gt rows in registers.
    float ax[8], ay[8], az[8], aw[8], rm[8];
    const float* gbase = gts + ((size_t)b * NN + rowBase + ty * 8) * 3;
#pragma unroll
    for (int g = 0; g < 8; ++g) {
        float x = gbase[g * 3 + 0];
        float y = gbase[g * 3 + 1];
        float z = gbase[g * 3 + 2];
        ax[g] = x; ay[g] = y; az[g] = z;
        aw[g] = x * x + y * y + z * z;
        rm[g] = kInf;
    }

    // Init block-local col mins.
#pragma unroll
    for (int i = 0; i < COL_TILE / 256; ++i) colmin[tid + 256 * i] = INF_BITS;

    const float* pbase = preds + (size_t)b * MM * 3;

    // Prologue: stage chunk 0.
    if (tid < CHUNK) {
        const float* p = pbase + (size_t)(colBase + tid) * 3;
        float x = p[0], y = p[1], z = p[2];
        sp[0][tid] = make_float4(x, y, z, -0.5f * (x * x + y * y + z * z));
    }
    __syncthreads();

    const int NCHUNK = COL_TILE / CHUNK;   // 16
    for (int j = 0; j < NCHUNK; ++j) {
        // Issue next chunk's global loads early (overlap with compute).
        float px = 0.f, py = 0.f, pz = 0.f;
        const bool st = (j + 1 < NCHUNK) && (tid < CHUNK);
        if (st) {
            const float* p = pbase + (size_t)(colBase + (j + 1) * CHUNK + tid) * 3;
            px = p[0]; py = p[1]; pz = p[2];
        }

        float cm[8];
#pragma unroll
        for (int k = 0; k < 8; ++k) cm[k] = kInf;

        const float4* buf = sp[j & 1];
#pragma unroll
        for (int k = 0; k < 8; k += 2) {
            float4 p0 = buf[tx + 16 * k];
            float4 p1 = buf[tx + 16 * k + 16];
#pragma unroll
            for (int g = 0; g < 8; g += 2) {
                float t00 = fmaf(ax[g],   p0.x, fmaf(ay[g],   p0.y, fmaf(az[g],   p0.z, p0.w)));
                float t01 = fmaf(ax[g],   p1.x, fmaf(ay[g],   p1.y, fmaf(az[g],   p1.z, p1.w)));
                float t10 = fmaf(ax[g+1], p0.x, fmaf(ay[g+1], p0.y, fmaf(az[g+1], p0.z, p0.w)));
                float t11 = fmaf(ax[g+1], p1.x, fmaf(ay[g+1], p1.y, fmaf(az[g+1], p1.z, p1.w)));
                float d00 = fmaf(-2.0f, t00, aw[g]);
                float d01 = fmaf(-2.0f, t01, aw[g]);
                float d10 = fmaf(-2.0f, t10, aw[g+1]);
                float d11 = fmaf(-2.0f, t11, aw[g+1]);
                // min3 patterns: row mins and col mins
                rm[g]   = fminf(fminf(rm[g],   d00), d01);
                rm[g+1] = fminf(fminf(rm[g+1], d10), d11);
                cm[k]   = fminf(fminf(cm[k],   d00), d10);
                cm[k+1] = fminf(fminf(cm[k+1], d01), d11);
            }
        }

        // Col-min: reduce across the 4 ty-groups in this wave, then LDS atomic.
#pragma unroll
        for (int k = 0; k < 8; ++k) {
            float v = cm[k];
            v = fminf(v, __shfl_xor(v, 16, 64));
            v = fminf(v, __shfl_xor(v, 32, 64));
            cm[k] = v;
        }
        if (lane < 16) {
#pragma unroll
            for (int k = 0; k < 8; ++k)
                atomicMin(&colmin[j * CHUNK + lane + 16 * k], __float_as_int(cm[k]));
        }

        // Commit next chunk to LDS (after compute so vmcnt wait lands late).
        if (st)
            sp[(j + 1) & 1][tid] = make_float4(px, py, pz,
                                               -0.5f * (px * px + py * py + pz * pz));
        __syncthreads();
    }

    // Row mins (partial over this col range): reduce across tx, one atomic per row.
#pragma unroll
    for (int g = 0; g < 8; ++g) {
        float v = rm[g];
        v = fminf(v, __shfl_xor(v, 1, 64));
        v = fminf(v, __shfl_xor(v, 2, 64));
        v = fminf(v, __shfl_xor(v, 4, 64));
        v = fminf(v, __shfl_xor(v, 8, 64));
        rm[g] = v;
    }
    if (tx == 0) {
        int* row = minn + (size_t)b * NN + rowBase + ty * 8;
#pragma unroll
        for (int g = 0; g < 8; ++g) atomicMin(&row[g], __float_as_int(rm[g]));
    }

    // Col mins: one coalesced atomic burst for this block's 2048 cols.
    int* colg = minp + (size_t)b * MM + colBase;
#pragma unroll
    for (int i = 0; i < COL_TILE / 256; ++i)
        atomicMin(&colg[tid + 256 * i], colmin[tid + 256 * i]);
}

// Reduce both min arrays to the final scalar; last block finalizes (ticket).
__global__ void chamfer_reduce(const int* __restrict__ mins,
                               float* __restrict__ accum,
                               float* __restrict__ out) {
    const int idx = blockIdx.x * blockDim.x + threadIdx.x;
    const int stride = gridDim.x * blockDim.x;
    const int* minn = mins;
    const int* minp = mins + BB * NN;

    float s0 = 0.0f, s1 = 0.0f;
    for (int i = idx; i < BB * NN; i += stride)
        s0 += fmaxf(__int_as_float(minn[i]), 0.0f);
    for (int i = idx; i < BB * MM; i += stride)
        s1 += fmaxf(__int_as_float(minp[i]), 0.0f);

#pragma unroll
    for (int m = 1; m < 64; m <<= 1) {
        s0 += __shfl_xor(s0, m, 64);
        s1 += __shfl_xor(s1, m, 64);
    }
    __shared__ float w0[4], w1[4];
    if ((threadIdx.x & 63) == 0) {
        w0[threadIdx.x >> 6] = s0;
        w1[threadIdx.x >> 6] = s1;
    }
    __syncthreads();
    if (threadIdx.x == 0) {
        atomicAdd(&accum[0], w0[0] + w0[1] + w0[2] + w0[3]);
        atomicAdd(&accum[1], w1[0] + w1[1] + w1[2] + w1[3]);
        __threadfence();
        int done = atomicAdd((int*)accum + 2, 1);
        if (done == (int)gridDim.x - 1) {
            float a0 = atomicAdd(&accum[0], 0.0f);   // coherent read
            float a1 = atomicAdd(&accum[1], 0.0f);
            out[0] = a0 / (float)(BB * NN) + a1 / (float)(BB * MM);
        }
    }
}

extern "C" void kernel_launch(void* const* d_in, const int* in_sizes, int n_in,
                              void* d_out, int out_size, void* d_ws, size_t ws_size,
                              hipStream_t stream) {
    const float* gts   = (const float*)d_in[0];
    const float* preds = (const float*)d_in[1];
    float* out = (float*)d_out;

    float* accum = (float*)d_ws;
    int* mins = (int*)((char*)d_ws + 64);   // minn[BB*NN] then minp[BB*MM]

    chamfer_init<<<(BB * (NN + MM) + 255) / 256, 256, 0, stream>>>(mins, accum);

    dim3 grid(NN / ROW_TILE, MM / COL_TILE, BB);   // 64 x 4 x 8 = 2048 blocks
    chamfer_main<<<grid, 256, 0, stream>>>(gts, preds, mins, mins + BB * NN);

    chamfer_reduce<<<64, 256, 0, stream>>>(mins, accum, out);
}

// Round 3
// 135.763 us; speedup vs baseline: 6.2907x; 6.2907x over previous
//
#include <hip/hip_runtime.h>
#include <math.h>

// Problem shape (fixed by the harness/reference):
#define BB 8
#define NN 8192
#define MM 8192
// D = 3

#define ROW_TILE 128      // rows per block (8 per thread, 16 ty)
#define COL_TILE 2048     // cols per block
#define CHUNK    128      // preds staged per iteration
#define INF_BITS 0x7F800000

// d_ws layout:
//   float accum[2]  : [0]=sum_g2p, [1]=sum_p2g
//   int   ticket    : at accum[2]
//   +64B  int minn[BB*NN]; int minp[BB*MM]   (float-bits, int-min trick)

__global__ void chamfer_init(int* __restrict__ mins, float* __restrict__ accum) {
    int idx = blockIdx.x * blockDim.x + threadIdx.x;
    if (idx < BB * (NN + MM)) mins[idx] = INF_BITS;
    if (idx < 2) accum[idx] = 0.0f;
    if (idx == 2) ((int*)accum)[2] = 0;
}

// __launch_bounds__(256, 4): cap 128 VGPR/wave. R2's (256,7) capped at 73 and
// spilled the 40-float register tile to scratch (VGPR=36, 3.5 GB HBM traffic,
// 4.8x regression). Actual demand ~80 VGPRs -> no spill at this bound.
__global__ __launch_bounds__(256, 4) void chamfer_main(
    const float* __restrict__ gts, const float* __restrict__ preds,
    int* __restrict__ minn, int* __restrict__ minp)
{
    __shared__ float4 sp[2][CHUNK];     // double-buffered pred chunk: x,y,z,-|p|^2/2
    __shared__ int colmin[COL_TILE];    // block-local col mins (float bits, int-min)

    const int b       = blockIdx.z;
    const int rowBase = blockIdx.x * ROW_TILE;
    const int colBase = blockIdx.y * COL_TILE;
    const int tid  = threadIdx.x;
    const int tx   = tid & 15;
    const int ty   = tid >> 4;
    const int lane = tid & 63;

    const float kInf = __builtin_inff();

    // This thread's 8 gt rows in registers.
    float ax[8], ay[8], az[8], aw[8], rm[8];
    const float* gbase = gts + ((size_t)b * NN + rowBase + ty * 8) * 3;
#pragma unroll
    for (int g = 0; g < 8; ++g) {
        float x = gbase[g * 3 + 0];
        float y = gbase[g * 3 + 1];
        float z = gbase[g * 3 + 2];
        ax[g] = x; ay[g] = y; az[g] = z;
        aw[g] = x * x + y * y + z * z;
        rm[g] = kInf;
    }

    // Init block-local col mins.
#pragma unroll
    for (int i = 0; i < COL_TILE / 256; ++i) colmin[tid + 256 * i] = INF_BITS;

    const float* pbase = preds + (size_t)b * MM * 3;

    // Prologue: stage chunk 0.
    if (tid < CHUNK) {
        const float* p = pbase + (size_t)(colBase + tid) * 3;
        float x = p[0], y = p[1], z = p[2];
        sp[0][tid] = make_float4(x, y, z, -0.5f * (x * x + y * y + z * z));
    }
    __syncthreads();

    const int NCHUNK = COL_TILE / CHUNK;   // 16
    for (int j = 0; j < NCHUNK; ++j) {
        // Issue next chunk's global loads early (overlap with compute).
        float px = 0.f, py = 0.f, pz = 0.f;
        const bool st = (j + 1 < NCHUNK) && (tid < CHUNK);
        if (st) {
            const float* p = pbase + (size_t)(colBase + (j + 1) * CHUNK + tid) * 3;
            px = p[0]; py = p[1]; pz = p[2];
        }

        float cm[8];
#pragma unroll
        for (int k = 0; k < 8; ++k) cm[k] = kInf;

        const float4* buf = sp[j & 1];
#pragma unroll
        for (int k = 0; k < 8; k += 2) {
            float4 p0 = buf[tx + 16 * k];
            float4 p1 = buf[tx + 16 * k + 16];
#pragma unroll
            for (int g = 0; g < 8; g += 2) {
                float t00 = fmaf(ax[g],   p0.x, fmaf(ay[g],   p0.y, fmaf(az[g],   p0.z, p0.w)));
                float t01 = fmaf(ax[g],   p1.x, fmaf(ay[g],   p1.y, fmaf(az[g],   p1.z, p1.w)));
                float t10 = fmaf(ax[g+1], p0.x, fmaf(ay[g+1], p0.y, fmaf(az[g+1], p0.z, p0.w)));
                float t11 = fmaf(ax[g+1], p1.x, fmaf(ay[g+1], p1.y, fmaf(az[g+1], p1.z, p1.w)));
                float d00 = fmaf(-2.0f, t00, aw[g]);
                float d01 = fmaf(-2.0f, t01, aw[g]);
                float d10 = fmaf(-2.0f, t10, aw[g+1]);
                float d11 = fmaf(-2.0f, t11, aw[g+1]);
                // min3 patterns: row mins and col mins
                rm[g]   = fminf(fminf(rm[g],   d00), d01);
                rm[g+1] = fminf(fminf(rm[g+1], d10), d11);
                cm[k]   = fminf(fminf(cm[k],   d00), d10);
                cm[k+1] = fminf(fminf(cm[k+1], d01), d11);
            }
        }

        // Col-min: reduce across the 4 ty-groups in this wave, then LDS atomic.
#pragma unroll
        for (int k = 0; k < 8; ++k) {
            float v = cm[k];
            v = fminf(v, __shfl_xor(v, 16, 64));
            v = fminf(v, __shfl_xor(v, 32, 64));
            cm[k] = v;
        }
        if (lane < 16) {
#pragma unroll
            for (int k = 0; k < 8; ++k)
                atomicMin(&colmin[j * CHUNK + lane + 16 * k], __float_as_int(cm[k]));
        }

        // Commit next chunk to LDS (after compute so vmcnt wait lands late).
        if (st)
            sp[(j + 1) & 1][tid] = make_float4(px, py, pz,
                                               -0.5f * (px * px + py * py + pz * pz));
        __syncthreads();
    }

    // Row mins (partial over this col range): reduce across tx, one atomic per row.
#pragma unroll
    for (int g = 0; g < 8; ++g) {
        float v = rm[g];
        v = fminf(v, __shfl_xor(v, 1, 64));
        v = fminf(v, __shfl_xor(v, 2, 64));
        v = fminf(v, __shfl_xor(v, 4, 64));
        v = fminf(v, __shfl_xor(v, 8, 64));
        rm[g] = v;
    }
    if (tx == 0) {
        int* row = minn + (size_t)b * NN + rowBase + ty * 8;
#pragma unroll
        for (int g = 0; g < 8; ++g) atomicMin(&row[g], __float_as_int(rm[g]));
    }

    // Col mins: one coalesced atomic burst for this block's 2048 cols.
    int* colg = minp + (size_t)b * MM + colBase;
#pragma unroll
    for (int i = 0; i < COL_TILE / 256; ++i)
        atomicMin(&colg[tid + 256 * i], colmin[tid + 256 * i]);
}

// Reduce both min arrays to the final scalar; last block finalizes (ticket).
__global__ void chamfer_reduce(const int* __restrict__ mins,
                               float* __restrict__ accum,
                               float* __restrict__ out) {
    const int idx = blockIdx.x * blockDim.x + threadIdx.x;
    const int stride = gridDim.x * blockDim.x;
    const int* minn = mins;
    const int* minp = mins + BB * NN;

    float s0 = 0.0f, s1 = 0.0f;
    for (int i = idx; i < BB * NN; i += stride)
        s0 += fmaxf(__int_as_float(minn[i]), 0.0f);
    for (int i = idx; i < BB * MM; i += stride)
        s1 += fmaxf(__int_as_float(minp[i]), 0.0f);

#pragma unroll
    for (int m = 1; m < 64; m <<= 1) {
        s0 += __shfl_xor(s0, m, 64);
        s1 += __shfl_xor(s1, m, 64);
    }
    __shared__ float w0[4], w1[4];
    if ((threadIdx.x & 63) == 0) {
        w0[threadIdx.x >> 6] = s0;
        w1[threadIdx.x >> 6] = s1;
    }
    __syncthreads();
    if (threadIdx.x == 0) {
        atomicAdd(&accum[0], w0[0] + w0[1] + w0[2] + w0[3]);
        atomicAdd(&accum[1], w1[0] + w1[1] + w1[2] + w1[3]);
        __threadfence();
        int done = atomicAdd((int*)accum + 2, 1);
        if (done == (int)gridDim.x - 1) {
            float a0 = atomicAdd(&accum[0], 0.0f);   // coherent read
            float a1 = atomicAdd(&accum[1], 0.0f);
            out[0] = a0 / (float)(BB * NN) + a1 / (float)(BB * MM);
        }
    }
}

extern "C" void kernel_launch(void* const* d_in, const int* in_sizes, int n_in,
                              void* d_out, int out_size, void* d_ws, size_t ws_size,
                              hipStream_t stream) {
    const float* gts   = (const float*)d_in[0];
    const float* preds = (const float*)d_in[1];
    float* out = (float*)d_out;

    float* accum = (float*)d_ws;
    int* mins = (int*)((char*)d_ws + 64);   // minn[BB*NN] then minp[BB*MM]

    chamfer_init<<<(BB * (NN + MM) + 255) / 256, 256, 0, stream>>>(mins, accum);

    dim3 grid(NN / ROW_TILE, MM / COL_TILE, BB);   // 64 x 4 x 8 = 2048 blocks
    chamfer_main<<<grid, 256, 0, stream>>>(gts, preds, mins, mins + BB * NN);

    chamfer_reduce<<<64, 256, 0, stream>>>(mins, accum, out);
}